// Round 1
// baseline (352.426 us; speedup 1.0000x reference)
//
#include <hip/hip_runtime.h>

#define N_NODES 50000
#define N_EDGES 800000
#define CAP 64

// ---------------- zero int buffer ----------------
__global__ void zero_int_kernel(int* __restrict__ p, int n) {
    int i = blockIdx.x * blockDim.x + threadIdx.x;
    if (i < n) p[i] = 0;
}

// ---------------- build fixed-capacity adjacency (dst -> list of src) ----------------
__global__ void build_adj_kernel(const int* __restrict__ ei,
                                 int* __restrict__ cursor,
                                 int* __restrict__ adj) {
    int e = blockIdx.x * blockDim.x + threadIdx.x;
    if (e >= N_EDGES) return;
    int src = ei[e];
    int dst = ei[N_EDGES + e];
    // guards keep us crash-safe even if index dtype assumption is wrong
    if ((unsigned)dst >= (unsigned)N_NODES) return;
    if ((unsigned)src >= (unsigned)N_NODES) src = 0;
    int pos = atomicAdd(&cursor[dst], 1);
    if (pos < CAP) adj[dst * CAP + pos] = src;
}

// ---------------- GEMM: C[M][N] = A[M][128] @ W[128][N] ----------------
// BM=128 rows/block, TK=32 k-tile, 256 threads, micro-tile MM x 8.
template <int N>
__global__ __launch_bounds__(256) void gemm_kernel(const float* __restrict__ A,
                                                   const float* __restrict__ W,
                                                   float* __restrict__ C, int M) {
    constexpr int K = 128;
    constexpr int TK = 32;
    constexpr int BM = 128;
    constexpr int LDA = TK + 1;  // 33 floats: odd stride -> conflict-free A reads
    __shared__ float As[BM * LDA];   // ~16.9 KB
    __shared__ float Ws[TK * N];     // 16 KB (N=128) or 8 KB (N=64)

    constexpr int TN_THREADS = N / 8;            // 16 or 8
    constexpr int TM_THREADS = 256 / TN_THREADS; // 16 or 32
    constexpr int MM = BM / TM_THREADS;          // 8 or 4

    const int tid = threadIdx.x;
    const int tn = tid % TN_THREADS;
    const int tm = tid / TN_THREADS;
    const int row0 = blockIdx.x * BM;

    float acc[MM][8];
#pragma unroll
    for (int i = 0; i < MM; i++)
#pragma unroll
        for (int j = 0; j < 8; j++) acc[i][j] = 0.f;

    for (int kt = 0; kt < K; kt += TK) {
        // stage A tile: BM x TK
        {
            int r = tid / 8;
            int c = (tid % 8) * 4;
#pragma unroll
            for (int i = 0; i < 4; i++) {
                int row = r + i * 32;
                int grow = row0 + row;
                float4 v = make_float4(0.f, 0.f, 0.f, 0.f);
                if (grow < M)
                    v = *reinterpret_cast<const float4*>(&A[(size_t)grow * K + kt + c]);
                As[row * LDA + c + 0] = v.x;
                As[row * LDA + c + 1] = v.y;
                As[row * LDA + c + 2] = v.z;
                As[row * LDA + c + 3] = v.w;
            }
        }
        // stage W tile: TK x N
        {
            constexpr int TOT4 = TK * N / 4;
            for (int i = tid; i < TOT4; i += 256) {
                int k = i / (N / 4);
                int c = (i % (N / 4)) * 4;
                float4 v = *reinterpret_cast<const float4*>(&W[(size_t)(kt + k) * N + c]);
                *reinterpret_cast<float4*>(&Ws[k * N + c]) = v;
            }
        }
        __syncthreads();
#pragma unroll
        for (int k = 0; k < TK; k++) {
            float a[MM], w[8];
#pragma unroll
            for (int i = 0; i < MM; i++) a[i] = As[(tm * MM + i) * LDA + k];
            float4 w0 = *reinterpret_cast<const float4*>(&Ws[k * N + tn * 8]);
            float4 w1 = *reinterpret_cast<const float4*>(&Ws[k * N + tn * 8 + 4]);
            w[0] = w0.x; w[1] = w0.y; w[2] = w0.z; w[3] = w0.w;
            w[4] = w1.x; w[5] = w1.y; w[6] = w1.z; w[7] = w1.w;
#pragma unroll
            for (int i = 0; i < MM; i++)
#pragma unroll
                for (int j = 0; j < 8; j++) acc[i][j] += a[i] * w[j];
        }
        __syncthreads();
    }
#pragma unroll
    for (int i = 0; i < MM; i++) {
        int grow = row0 + tm * MM + i;
        if (grow < M) {
            float4 v0 = make_float4(acc[i][0], acc[i][1], acc[i][2], acc[i][3]);
            float4 v1 = make_float4(acc[i][4], acc[i][5], acc[i][6], acc[i][7]);
            *reinterpret_cast<float4*>(&C[(size_t)grow * N + tn * 8 + 0]) = v0;
            *reinterpret_cast<float4*>(&C[(size_t)grow * N + tn * 8 + 4]) = v1;
        }
    }
}

// ---------------- aggregate: out[n] = bias + sum_{e in adj[n]} hw[src_e] ----------------
// one 64-lane wave per node; lane handles F/64 contiguous floats (float2 for F=128)
template <int F>
__global__ __launch_bounds__(256) void aggregate_kernel(const float* __restrict__ hw,
                                                        const int* __restrict__ adj,
                                                        const int* __restrict__ deg,
                                                        const float* __restrict__ bias,
                                                        float* __restrict__ out) {
    int wave = (blockIdx.x * blockDim.x + threadIdx.x) >> 6;
    int lane = threadIdx.x & 63;
    if (wave >= N_NODES) return;
    const int n = wave;
    int d = deg[n];
    d = __builtin_amdgcn_readfirstlane(d);
    if (d > CAP) d = CAP;
    const int* al = &adj[n * CAP];
    int myslot = al[lane];  // cooperative load of the whole edge list (CAP==64)

    if (F == 128) {
        float2 acc = make_float2(0.f, 0.f);
        for (int e = 0; e < d; e++) {
            int s = __shfl(myslot, e);
            float2 v = *reinterpret_cast<const float2*>(&hw[(size_t)s * 128 + lane * 2]);
            acc.x += v.x;
            acc.y += v.y;
        }
        float2 b = *reinterpret_cast<const float2*>(&bias[lane * 2]);
        acc.x += b.x;
        acc.y += b.y;
        *reinterpret_cast<float2*>(&out[(size_t)n * 128 + lane * 2]) = acc;
    } else {
        float acc = 0.f;
        for (int e = 0; e < d; e++) {
            int s = __shfl(myslot, e);
            acc += hw[(size_t)s * 64 + lane];
        }
        out[(size_t)n * 64 + lane] = acc + bias[lane];
    }
}

extern "C" void kernel_launch(void* const* d_in, const int* in_sizes, int n_in,
                              void* d_out, int out_size, void* d_ws, size_t ws_size,
                              hipStream_t stream) {
    const float* x  = (const float*)d_in[0];
    const int*   ei = (const int*)d_in[1];
    const float* W1 = (const float*)d_in[2];
    const float* b1 = (const float*)d_in[3];
    const float* W2 = (const float*)d_in[4];
    const float* b2 = (const float*)d_in[5];
    const float* W3 = (const float*)d_in[6];
    const float* b3 = (const float*)d_in[7];

    float* o1 = (float*)d_out;                       // [50000,128]
    float* o2 = o1 + (size_t)N_NODES * 128;          // [50000,128]
    float* o3 = o2 + (size_t)N_NODES * 128;          // [50000,64]

    char* ws = (char*)d_ws;
    float* hw    = (float*)ws;                                  // 25.6 MB
    int*   adj   = (int*)(ws + (size_t)N_NODES * 128 * 4);      // 12.8 MB
    int*   cursor= (int*)(ws + (size_t)N_NODES * 128 * 4 + (size_t)N_NODES * CAP * 4); // 200 KB

    // build adjacency (once per call; reused by all 3 layers)
    zero_int_kernel<<<(N_NODES + 255) / 256, 256, 0, stream>>>(cursor, N_NODES);
    build_adj_kernel<<<(N_EDGES + 255) / 256, 256, 0, stream>>>(ei, cursor, adj);

    const int gemm_grid = (N_NODES + 127) / 128;
    const int agg_grid = (N_NODES * 64 + 255) / 256;

    // layer 1
    gemm_kernel<128><<<gemm_grid, 256, 0, stream>>>(x, W1, hw, N_NODES);
    aggregate_kernel<128><<<agg_grid, 256, 0, stream>>>(hw, adj, cursor, b1, o1);
    // layer 2
    gemm_kernel<128><<<gemm_grid, 256, 0, stream>>>(o1, W2, hw, N_NODES);
    aggregate_kernel<128><<<agg_grid, 256, 0, stream>>>(hw, adj, cursor, b2, o2);
    // layer 3
    gemm_kernel<64><<<gemm_grid, 256, 0, stream>>>(o2, W3, hw, N_NODES);
    aggregate_kernel<64><<<agg_grid, 256, 0, stream>>>(hw, adj, cursor, b3, o3);
}

// Round 2
// 294.937 us; speedup vs baseline: 1.1949x; 1.1949x over previous
//
#include <hip/hip_runtime.h>

#define N_NODES 50000
#define N_EDGES 800000
#define CAP 64

typedef unsigned int uint32;

__device__ __forceinline__ uint32 f32_to_bf16_rne(float f) {
    uint32 u = __float_as_uint(f);
    u += 0x7fffu + ((u >> 16) & 1u);
    return u >> 16;
}
__device__ __forceinline__ float bf16lo_to_f32(uint32 v) {  // low 16 bits
    return __uint_as_float(v << 16);
}
__device__ __forceinline__ float bf16hi_to_f32(uint32 v) {  // high 16 bits
    return __uint_as_float(v & 0xffff0000u);
}

// ---------------- zero int buffer ----------------
__global__ void zero_int_kernel(int* __restrict__ p, int n) {
    int i = blockIdx.x * blockDim.x + threadIdx.x;
    if (i < n) p[i] = 0;
}

// ---------------- build fixed-capacity adjacency (dst -> list of src) ----------------
__global__ void build_adj_kernel(const int* __restrict__ ei,
                                 int* __restrict__ cursor,
                                 int* __restrict__ adj) {
    int e = blockIdx.x * blockDim.x + threadIdx.x;
    if (e >= N_EDGES) return;
    int src = ei[e];
    int dst = ei[N_EDGES + e];
    if ((unsigned)dst >= (unsigned)N_NODES) return;
    if ((unsigned)src >= (unsigned)N_NODES) src = 0;
    int pos = atomicAdd(&cursor[dst], 1);
    if (pos < CAP) adj[dst * CAP + pos] = src;
}

// ---------------- GEMM: Cbf16[M][N] = A_f32[M][128] @ W_f32[128][N] ----------------
// BM=64 rows/block, TK=32, 256 threads. Writes bf16-packed C (2 feats/uint).
template <int N>
__global__ __launch_bounds__(256) void gemm_kernel(const float* __restrict__ A,
                                                   const float* __restrict__ W,
                                                   uint32* __restrict__ Cb, int M) {
    constexpr int K = 128;
    constexpr int TK = 32;
    constexpr int BM = 64;
    constexpr int LDA = TK + 1;      // 33: odd stride -> conflict-free A reads
    __shared__ float As[BM * LDA];   // 8.4 KB
    __shared__ float Ws[TK * N];     // 16 KB (N=128) / 8 KB (N=64)

    constexpr int TN_THREADS = N / 8;             // 16 or 8
    constexpr int TM_THREADS = 256 / TN_THREADS;  // 16 or 32
    constexpr int MM = BM / TM_THREADS;           // 4 or 2

    const int tid = threadIdx.x;
    const int tn = tid % TN_THREADS;
    const int tm = tid / TN_THREADS;
    const int row0 = blockIdx.x * BM;

    float acc[MM][8];
#pragma unroll
    for (int i = 0; i < MM; i++)
#pragma unroll
        for (int j = 0; j < 8; j++) acc[i][j] = 0.f;

    for (int kt = 0; kt < K; kt += TK) {
        // stage A tile: BM(64) x TK(32) = 2048 floats; 256 thr x 2 float4
        {
            int r = tid / 8;            // 0..31
            int c = (tid % 8) * 4;      // 0..28
#pragma unroll
            for (int i = 0; i < 2; i++) {
                int row = r + i * 32;
                int grow = row0 + row;
                float4 v = make_float4(0.f, 0.f, 0.f, 0.f);
                if (grow < M)
                    v = *reinterpret_cast<const float4*>(&A[(size_t)grow * K + kt + c]);
                As[row * LDA + c + 0] = v.x;
                As[row * LDA + c + 1] = v.y;
                As[row * LDA + c + 2] = v.z;
                As[row * LDA + c + 3] = v.w;
            }
        }
        // stage W tile: TK x N
        {
            constexpr int TOT4 = TK * N / 4;
#pragma unroll
            for (int i = tid; i < TOT4; i += 256) {
                int k = i / (N / 4);
                int c = (i % (N / 4)) * 4;
                *reinterpret_cast<float4*>(&Ws[k * N + c]) =
                    *reinterpret_cast<const float4*>(&W[(size_t)(kt + k) * N + c]);
            }
        }
        __syncthreads();
#pragma unroll
        for (int k = 0; k < TK; k++) {
            float a[MM], w[8];
#pragma unroll
            for (int i = 0; i < MM; i++) a[i] = As[(tm * MM + i) * LDA + k];
            float4 w0 = *reinterpret_cast<const float4*>(&Ws[k * N + tn * 8]);
            float4 w1 = *reinterpret_cast<const float4*>(&Ws[k * N + tn * 8 + 4]);
            w[0] = w0.x; w[1] = w0.y; w[2] = w0.z; w[3] = w0.w;
            w[4] = w1.x; w[5] = w1.y; w[6] = w1.z; w[7] = w1.w;
#pragma unroll
            for (int i = 0; i < MM; i++)
#pragma unroll
                for (int j = 0; j < 8; j++) acc[i][j] += a[i] * w[j];
        }
        __syncthreads();
    }
    // epilogue: pack 8 f32 -> 4 uints (bf16 pairs), one uint4 store per row
#pragma unroll
    for (int i = 0; i < MM; i++) {
        int grow = row0 + tm * MM + i;
        if (grow < M) {
            uint4 p;
            p.x = f32_to_bf16_rne(acc[i][0]) | (f32_to_bf16_rne(acc[i][1]) << 16);
            p.y = f32_to_bf16_rne(acc[i][2]) | (f32_to_bf16_rne(acc[i][3]) << 16);
            p.z = f32_to_bf16_rne(acc[i][4]) | (f32_to_bf16_rne(acc[i][5]) << 16);
            p.w = f32_to_bf16_rne(acc[i][6]) | (f32_to_bf16_rne(acc[i][7]) << 16);
            *reinterpret_cast<uint4*>(&Cb[((size_t)grow * N + tn * 8) >> 1]) = p;
        }
    }
}

// ---------------- aggregate F=128: one wave per node, bf16 gather ----------------
__global__ __launch_bounds__(256) void aggregate128_kernel(const uint32* __restrict__ hwb,
                                                           const int* __restrict__ adj,
                                                           const int* __restrict__ deg,
                                                           const float* __restrict__ bias,
                                                           float* __restrict__ out) {
    int wave = (blockIdx.x * blockDim.x + threadIdx.x) >> 6;
    int lane = threadIdx.x & 63;
    if (wave >= N_NODES) return;
    const int n = wave;
    int d = deg[n];
    d = __builtin_amdgcn_readfirstlane(d);
    if (d > CAP) d = CAP;
    int myslot = adj[n * CAP + lane];

    float ax = 0.f, ay = 0.f;
    for (int e = 0; e < d; e++) {
        int s = __shfl(myslot, e);
        uint32 v = hwb[(size_t)s * 64 + lane];  // 2 bf16 feats: 2*lane, 2*lane+1
        ax += bf16lo_to_f32(v);
        ay += bf16hi_to_f32(v);
    }
    float2 b = *reinterpret_cast<const float2*>(&bias[lane * 2]);
    float2 r = make_float2(ax + b.x, ay + b.y);
    *reinterpret_cast<float2*>(&out[(size_t)n * 128 + lane * 2]) = r;
}

// ---------------- aggregate F=64: two nodes per wave (32 lanes each), bf16 gather ----
__global__ __launch_bounds__(256) void aggregate64_kernel(const uint32* __restrict__ hwb,
                                                          const int* __restrict__ adj,
                                                          const int* __restrict__ deg,
                                                          const float* __restrict__ bias,
                                                          float* __restrict__ out) {
    int wave = (blockIdx.x * blockDim.x + threadIdx.x) >> 6;
    int lane = threadIdx.x & 63;
    if (wave >= N_NODES / 2) return;
    const int half = lane >> 5;     // 0: node a, 1: node b
    const int li = lane & 31;
    const int a = wave * 2;

    int slotA = adj[a * CAP + lane];
    int slotB = adj[(a + 1) * CAP + lane];
    int dmine = deg[a + half];
    int d0 = __shfl(dmine, 0);
    int d1 = __shfl(dmine, 32);
    if (d0 > CAP) d0 = CAP;
    if (d1 > CAP) d1 = CAP;
    int dH = half ? d1 : d0;
    int dmax = d0 > d1 ? d0 : d1;

    float ax = 0.f, ay = 0.f;
    for (int e = 0; e < dmax; e++) {
        int sA = __shfl(slotA, e);
        int sB = __shfl(slotB, e);
        int s = half ? sB : sA;
        if (e < dH) {
            uint32 v = hwb[(size_t)s * 32 + li];  // feats 2*li, 2*li+1
            ax += bf16lo_to_f32(v);
            ay += bf16hi_to_f32(v);
        }
    }
    float2 b = *reinterpret_cast<const float2*>(&bias[li * 2]);
    float2 r = make_float2(ax + b.x, ay + b.y);
    *reinterpret_cast<float2*>(&out[(size_t)(a + half) * 64 + li * 2]) = r;
}

extern "C" void kernel_launch(void* const* d_in, const int* in_sizes, int n_in,
                              void* d_out, int out_size, void* d_ws, size_t ws_size,
                              hipStream_t stream) {
    const float* x  = (const float*)d_in[0];
    const int*   ei = (const int*)d_in[1];
    const float* W1 = (const float*)d_in[2];
    const float* b1 = (const float*)d_in[3];
    const float* W2 = (const float*)d_in[4];
    const float* b2 = (const float*)d_in[5];
    const float* W3 = (const float*)d_in[6];
    const float* b3 = (const float*)d_in[7];

    float* o1 = (float*)d_out;                       // [50000,128]
    float* o2 = o1 + (size_t)N_NODES * 128;          // [50000,128]
    float* o3 = o2 + (size_t)N_NODES * 128;          // [50000,64]

    char* ws = (char*)d_ws;
    uint32* hwb  = (uint32*)ws;                                   // bf16-packed, 12.8 MB
    int* adj     = (int*)(ws + (size_t)N_NODES * 64 * 4);         // 12.8 MB
    int* cursor  = (int*)(ws + (size_t)N_NODES * 64 * 4 + (size_t)N_NODES * CAP * 4);

    zero_int_kernel<<<(N_NODES + 255) / 256, 256, 0, stream>>>(cursor, N_NODES);
    build_adj_kernel<<<(N_EDGES + 255) / 256, 256, 0, stream>>>(ei, cursor, adj);

    const int gemm_grid = (N_NODES + 63) / 64;          // 782
    const int agg128_grid = (N_NODES * 64 + 255) / 256; // 12500
    const int agg64_grid = (N_NODES / 2 * 64 + 255) / 256;

    // layer 1
    gemm_kernel<128><<<gemm_grid, 256, 0, stream>>>(x, W1, hwb, N_NODES);
    aggregate128_kernel<<<agg128_grid, 256, 0, stream>>>(hwb, adj, cursor, b1, o1);
    // layer 2
    gemm_kernel<128><<<gemm_grid, 256, 0, stream>>>(o1, W2, hwb, N_NODES);
    aggregate128_kernel<<<agg128_grid, 256, 0, stream>>>(hwb, adj, cursor, b2, o2);
    // layer 3
    gemm_kernel<64><<<gemm_grid, 256, 0, stream>>>(o2, W3, hwb, N_NODES);
    aggregate64_kernel<<<agg64_grid, 256, 0, stream>>>(hwb, adj, cursor, b3, o3);
}

// Round 3
// 204.208 us; speedup vs baseline: 1.7258x; 1.4443x over previous
//
#include <hip/hip_runtime.h>

#define N_NODES 50000
#define N_EDGES 800000
#define CAP 64

typedef unsigned int uint32;
typedef unsigned short ushort16;

typedef __attribute__((ext_vector_type(8))) short bf16x8;
typedef __attribute__((ext_vector_type(4))) float f32x4;

__device__ __forceinline__ uint32 f32_to_bf16_rne(float f) {
    uint32 u = __float_as_uint(f);
    u += 0x7fffu + ((u >> 16) & 1u);
    return u >> 16;
}
__device__ __forceinline__ float bf16lo_to_f32(uint32 v) { return __uint_as_float(v << 16); }
__device__ __forceinline__ float bf16hi_to_f32(uint32 v) { return __uint_as_float(v & 0xffff0000u); }

// ---------------- zero int buffer ----------------
__global__ void zero_int_kernel(int* __restrict__ p, int n) {
    int i = blockIdx.x * blockDim.x + threadIdx.x;
    if (i < n) p[i] = 0;
}

// ---------------- build fixed-capacity adjacency (dst -> list of src), ushort ----
__global__ void build_adj_kernel(const int* __restrict__ ei,
                                 int* __restrict__ cursor,
                                 ushort16* __restrict__ adj) {
    int e = blockIdx.x * blockDim.x + threadIdx.x;
    if (e >= N_EDGES) return;
    int src = ei[e];
    int dst = ei[N_EDGES + e];
    if ((unsigned)dst >= (unsigned)N_NODES) return;
    if ((unsigned)src >= (unsigned)N_NODES) src = 0;
    int pos = atomicAdd(&cursor[dst], 1);
    if (pos < CAP) adj[dst * CAP + pos] = (ushort16)src;
}

// ---------------- f32 -> packed bf16 convert (float4 per thread) ----------------
__global__ void cvt_kernel(const float* __restrict__ in, uint32* __restrict__ out, int n4) {
    int i = blockIdx.x * blockDim.x + threadIdx.x;
    if (i >= n4) return;
    float4 v = reinterpret_cast<const float4*>(in)[i];
    uint2 p;
    p.x = f32_to_bf16_rne(v.x) | (f32_to_bf16_rne(v.y) << 16);
    p.y = f32_to_bf16_rne(v.z) | (f32_to_bf16_rne(v.w) << 16);
    reinterpret_cast<uint2*>(out)[i] = p;
}

// ---------------- W [K=128][N] f32  ->  WT packed bf16 [N][64] ----------------
__global__ void wt_kernel(const float* __restrict__ W, uint32* __restrict__ WTb, int N) {
    int i = blockIdx.x * blockDim.x + threadIdx.x;  // over N*64
    if (i >= N * 64) return;
    int n = i >> 6;
    int p = i & 63;
    float lo = W[(2 * p) * N + n];
    float hi = W[(2 * p + 1) * N + n];
    WTb[n * 64 + p] = f32_to_bf16_rne(lo) | (f32_to_bf16_rne(hi) << 16);
}

// ---------------- MFMA GEMM: Cb[M][N/2] = bf16(A[M][128] @ W[128][N]) -----------
// Ab: packed bf16 [M][64], WTb: packed bf16 [N][64]. No LDS; 4 waves/block.
// Wave computes 64 rows x 16 cols. Grid: (ceil(M/64), N/64).
template <int N>
__global__ __launch_bounds__(256) void mfma_gemm_kernel(const uint32* __restrict__ Ab,
                                                        const uint32* __restrict__ WTb,
                                                        uint32* __restrict__ Cb, int M) {
    const int tid = threadIdx.x;
    const int wave = tid >> 6;
    const int lane = tid & 63;
    const int r16 = lane & 15;
    const int g = lane >> 4;  // k-group 0..3
    const int row0 = blockIdx.x * 64;
    const int col0 = blockIdx.y * 64 + wave * 16;

    const uint4* A4 = reinterpret_cast<const uint4*>(Ab);    // 16 uint4 per row
    const uint4* B4 = reinterpret_cast<const uint4*>(WTb);

    f32x4 acc[4];
#pragma unroll
    for (int m = 0; m < 4; m++) acc[m] = (f32x4){0.f, 0.f, 0.f, 0.f};

    union U { uint4 u; bf16x8 v; };

#pragma unroll
    for (int kt = 0; kt < 4; kt++) {  // K=128 in 4 steps of 32
        U b;
        b.u = B4[(col0 + r16) * 16 + kt * 4 + g];
        U a[4];
#pragma unroll
        for (int m = 0; m < 4; m++) {
            int row = row0 + m * 16 + r16;  // OOB rows read harmless ws garbage
            a[m].u = A4[row * 16 + kt * 4 + g];
        }
#pragma unroll
        for (int m = 0; m < 4; m++)
            acc[m] = __builtin_amdgcn_mfma_f32_16x16x32_bf16(a[m].v, b.v, acc[m], 0, 0, 0);
    }

    // epilogue: C[row][col], row=(lane>>4)*4+reg, col=lane&15 (verified layout).
    // pack col pairs via shfl_xor(1); even-col lanes store uint32.
#pragma unroll
    for (int m = 0; m < 4; m++) {
#pragma unroll
        for (int r = 0; r < 4; r++) {
            int row = row0 + m * 16 + g * 4 + r;
            float v = acc[m][r];
            float nb = __shfl_xor(v, 1);
            if ((r16 & 1) == 0 && row < M) {
                uint32 p = f32_to_bf16_rne(v) | (f32_to_bf16_rne(nb) << 16);
                int col = col0 + r16;
                Cb[(size_t)row * (N / 2) + (col >> 1)] = p;
            }
        }
    }
}

// ---------------- aggregate F=128: one wave/node, 8-deep unrolled gather --------
__global__ __launch_bounds__(256) void aggregate128_kernel(const uint32* __restrict__ hwb,
                                                           const ushort16* __restrict__ adj,
                                                           const int* __restrict__ deg,
                                                           const float* __restrict__ bias,
                                                           float* __restrict__ out,
                                                           uint32* __restrict__ obf) {
    int wave = (blockIdx.x * blockDim.x + threadIdx.x) >> 6;
    int lane = threadIdx.x & 63;
    if (wave >= N_NODES) return;
    int d = deg[wave];
    d = __builtin_amdgcn_readfirstlane(d);
    if (d > CAP) d = CAP;
    int myslot = adj[wave * CAP + lane];

    float ax = 0.f, ay = 0.f;
    int e = 0;
    for (; e + 8 <= d; e += 8) {
        int s0 = __shfl(myslot, e + 0), s1 = __shfl(myslot, e + 1);
        int s2 = __shfl(myslot, e + 2), s3 = __shfl(myslot, e + 3);
        int s4 = __shfl(myslot, e + 4), s5 = __shfl(myslot, e + 5);
        int s6 = __shfl(myslot, e + 6), s7 = __shfl(myslot, e + 7);
        uint32 v0 = hwb[s0 * 64 + lane], v1 = hwb[s1 * 64 + lane];
        uint32 v2 = hwb[s2 * 64 + lane], v3 = hwb[s3 * 64 + lane];
        uint32 v4 = hwb[s4 * 64 + lane], v5 = hwb[s5 * 64 + lane];
        uint32 v6 = hwb[s6 * 64 + lane], v7 = hwb[s7 * 64 + lane];
        ax += (bf16lo_to_f32(v0) + bf16lo_to_f32(v1)) + (bf16lo_to_f32(v2) + bf16lo_to_f32(v3)) +
              (bf16lo_to_f32(v4) + bf16lo_to_f32(v5)) + (bf16lo_to_f32(v6) + bf16lo_to_f32(v7));
        ay += (bf16hi_to_f32(v0) + bf16hi_to_f32(v1)) + (bf16hi_to_f32(v2) + bf16hi_to_f32(v3)) +
              (bf16hi_to_f32(v4) + bf16hi_to_f32(v5)) + (bf16hi_to_f32(v6) + bf16hi_to_f32(v7));
    }
    for (; e < d; e++) {
        int s = __shfl(myslot, e);
        uint32 v = hwb[s * 64 + lane];
        ax += bf16lo_to_f32(v);
        ay += bf16hi_to_f32(v);
    }
    float2 b = *reinterpret_cast<const float2*>(&bias[lane * 2]);
    ax += b.x;
    ay += b.y;
    *reinterpret_cast<float2*>(&out[(size_t)wave * 128 + lane * 2]) = make_float2(ax, ay);
    if (obf) obf[wave * 64 + lane] = f32_to_bf16_rne(ax) | (f32_to_bf16_rne(ay) << 16);
}

// ---------------- aggregate F=64: two nodes/wave, 4-deep predicated unroll ------
__global__ __launch_bounds__(256) void aggregate64_kernel(const uint32* __restrict__ hwb,
                                                          const ushort16* __restrict__ adj,
                                                          const int* __restrict__ deg,
                                                          const float* __restrict__ bias,
                                                          float* __restrict__ out) {
    int wave = (blockIdx.x * blockDim.x + threadIdx.x) >> 6;
    int lane = threadIdx.x & 63;
    if (wave >= N_NODES / 2) return;
    const int half = lane >> 5;
    const int li = lane & 31;
    const int a = wave * 2;

    int slotA = adj[a * CAP + lane];
    int slotB = adj[(a + 1) * CAP + lane];
    int dmine = deg[a + half];
    int d0 = __shfl(dmine, 0);
    int d1 = __shfl(dmine, 32);
    if (d0 > CAP) d0 = CAP;
    if (d1 > CAP) d1 = CAP;
    int dH = half ? d1 : d0;
    int dmax = d0 > d1 ? d0 : d1;

    float ax = 0.f, ay = 0.f;
    int e = 0;
    for (; e + 4 <= dmax; e += 4) {
#pragma unroll
        for (int i = 0; i < 4; i++) {
            int sA = __shfl(slotA, e + i);
            int sB = __shfl(slotB, e + i);
            int s = half ? sB : sA;
            uint32 v = (e + i < dH) ? hwb[s * 32 + li] : 0u;
            ax += bf16lo_to_f32(v);
            ay += bf16hi_to_f32(v);
        }
    }
    for (; e < dmax; e++) {
        int sA = __shfl(slotA, e);
        int sB = __shfl(slotB, e);
        int s = half ? sB : sA;
        uint32 v = (e < dH) ? hwb[s * 32 + li] : 0u;
        ax += bf16lo_to_f32(v);
        ay += bf16hi_to_f32(v);
    }
    float2 b = *reinterpret_cast<const float2*>(&bias[li * 2]);
    ax += b.x;
    ay += b.y;
    *reinterpret_cast<float2*>(&out[(size_t)(a + half) * 64 + li * 2]) = make_float2(ax, ay);
}

extern "C" void kernel_launch(void* const* d_in, const int* in_sizes, int n_in,
                              void* d_out, int out_size, void* d_ws, size_t ws_size,
                              hipStream_t stream) {
    const float* x  = (const float*)d_in[0];
    const int*   ei = (const int*)d_in[1];
    const float* W1 = (const float*)d_in[2];
    const float* b1 = (const float*)d_in[3];
    const float* W2 = (const float*)d_in[4];
    const float* b2 = (const float*)d_in[5];
    const float* W3 = (const float*)d_in[6];
    const float* b3 = (const float*)d_in[7];

    float* o1 = (float*)d_out;
    float* o2 = o1 + (size_t)N_NODES * 128;
    float* o3 = o2 + (size_t)N_NODES * 128;

    char* ws = (char*)d_ws;
    uint32*   abf    = (uint32*)(ws);                    // A bf16-packed [M][64], 12.8 MB
    uint32*   hwb    = (uint32*)(ws + 12800000);         // h@W bf16-packed, 12.8 MB
    ushort16* adj    = (ushort16*)(ws + 25600000);       // 6.4 MB
    int*      cursor = (int*)(ws + 32000000);            // 200 KB
    uint32*   wt1    = (uint32*)(ws + 32200000);         // 32 KB
    uint32*   wt2    = (uint32*)(ws + 32232768);         // 32 KB
    uint32*   wt3    = (uint32*)(ws + 32265536);         // 16 KB

    zero_int_kernel<<<(N_NODES + 255) / 256, 256, 0, stream>>>(cursor, N_NODES);
    build_adj_kernel<<<(N_EDGES + 255) / 256, 256, 0, stream>>>(ei, cursor, adj);

    cvt_kernel<<<(N_NODES * 128 / 4 + 255) / 256, 256, 0, stream>>>(x, abf, N_NODES * 128 / 4);
    wt_kernel<<<(128 * 64 + 255) / 256, 256, 0, stream>>>(W1, wt1, 128);
    wt_kernel<<<(128 * 64 + 255) / 256, 256, 0, stream>>>(W2, wt2, 128);
    wt_kernel<<<(64 * 64 + 255) / 256, 256, 0, stream>>>(W3, wt3, 64);

    const dim3 gemm128_grid((N_NODES + 63) / 64, 2);
    const dim3 gemm64_grid((N_NODES + 63) / 64, 1);
    const int agg128_grid = (N_NODES * 64 + 255) / 256;
    const int agg64_grid = (N_NODES / 2 * 64 + 255) / 256;

    // layer 1
    mfma_gemm_kernel<128><<<gemm128_grid, 256, 0, stream>>>(abf, wt1, hwb, N_NODES);
    aggregate128_kernel<<<agg128_grid, 256, 0, stream>>>(hwb, adj, cursor, b1, o1, abf);
    // layer 2
    mfma_gemm_kernel<128><<<gemm128_grid, 256, 0, stream>>>(abf, wt2, hwb, N_NODES);
    aggregate128_kernel<<<agg128_grid, 256, 0, stream>>>(hwb, adj, cursor, b2, o2, abf);
    // layer 3
    mfma_gemm_kernel<64><<<gemm64_grid, 256, 0, stream>>>(abf, wt3, hwb, N_NODES);
    aggregate64_kernel<<<agg64_grid, 256, 0, stream>>>(hwb, adj, cursor, b3, o3);
}

// Round 4
// 203.486 us; speedup vs baseline: 1.7319x; 1.0035x over previous
//
#include <hip/hip_runtime.h>

#define N_NODES 50000
#define N_EDGES 800000
#define CAP 64

typedef unsigned int uint32;
typedef unsigned short u16;

typedef __attribute__((ext_vector_type(8))) short bf16x8;
typedef __attribute__((ext_vector_type(4))) float f32x4;

__device__ __forceinline__ uint32 f32_to_bf16_rne(float f) {
    uint32 u = __float_as_uint(f);
    u += 0x7fffu + ((u >> 16) & 1u);
    return u >> 16;
}
__device__ __forceinline__ float bf16lo_to_f32(uint32 v) { return __uint_as_float(v << 16); }
__device__ __forceinline__ float bf16hi_to_f32(uint32 v) { return __uint_as_float(v & 0xffff0000u); }

// ---------------- zero int buffer ----------------
__global__ void zero_int_kernel(int* __restrict__ p, int n) {
    int i = blockIdx.x * blockDim.x + threadIdx.x;
    if (i < n) p[i] = 0;
}

// ---------- XCD-partitioned adjacency build: block b commits only (dst&7)==(b&7) ----------
// Writes to a node's adjacency line then come (heuristically) from ONE XCD -> no line ping-pong.
#define EPT 8
#define EPB (256 * EPT)
__global__ __launch_bounds__(256) void build_adj_kernel(const int* __restrict__ ei,
                                                        int* __restrict__ cursor,
                                                        u16* __restrict__ adj) {
    const int part = blockIdx.x & 7;
    const int chunk = blockIdx.x >> 3;
    const int base = chunk * EPB + threadIdx.x * EPT;
#pragma unroll
    for (int i = 0; i < EPT; i += 4) {
        int e = base + i;
        if (e + 3 < N_EDGES) {
            int4 s4 = *reinterpret_cast<const int4*>(&ei[e]);
            int4 d4 = *reinterpret_cast<const int4*>(&ei[N_EDGES + e]);
            int ss[4] = {s4.x, s4.y, s4.z, s4.w};
            int dd[4] = {d4.x, d4.y, d4.z, d4.w};
#pragma unroll
            for (int j = 0; j < 4; j++) {
                int d = dd[j];
                if ((d & 7) == part && (unsigned)d < (unsigned)N_NODES) {
                    int s = ss[j];
                    if ((unsigned)s >= (unsigned)N_NODES) s = 0;
                    int pos = atomicAdd(&cursor[d], 1);
                    if (pos < CAP) adj[d * CAP + pos] = (u16)s;
                }
            }
        } else {
            for (int j = 0; j < 4; j++) {
                int ee = e + j;
                if (ee < N_EDGES) {
                    int d = ei[N_EDGES + ee];
                    if ((d & 7) == part && (unsigned)d < (unsigned)N_NODES) {
                        int s = ei[ee];
                        if ((unsigned)s >= (unsigned)N_NODES) s = 0;
                        int pos = atomicAdd(&cursor[d], 1);
                        if (pos < CAP) adj[d * CAP + pos] = (u16)s;
                    }
                }
            }
        }
    }
}

// ---------------- W [K=128][N] f32  ->  WT packed bf16 [N][64] ----------------
__global__ void wt_kernel(const float* __restrict__ W, uint32* __restrict__ WTb, int N) {
    int i = blockIdx.x * blockDim.x + threadIdx.x;  // over N*64
    if (i >= N * 64) return;
    int n = i >> 6;
    int p = i & 63;
    float lo = W[(2 * p) * N + n];
    float hi = W[(2 * p + 1) * N + n];
    WTb[n * 64 + p] = f32_to_bf16_rne(lo) | (f32_to_bf16_rne(hi) << 16);
}

// ---------------- MFMA GEMM, f32 A read directly (converted in-register) ----------------
// Cb[M][N/2 uint32] = bf16(A_f32[M][128] @ W[128][N]). Block: 64 rows x N cols, 4 waves.
// Wave: 64 rows x 16 cols x NT col-tiles (stride 64). Grid: ceil(M/64). No LDS.
template <int N>
__global__ __launch_bounds__(256) void mfma_gemm_kernel(const float* __restrict__ A,
                                                        const uint32* __restrict__ WTb,
                                                        uint32* __restrict__ Cb, int M) {
    constexpr int NT = N / 64;  // 2 for N=128, 1 for N=64
    const int tid = threadIdx.x;
    const int wave = tid >> 6;
    const int lane = tid & 63;
    const int r16 = lane & 15;
    const int g = lane >> 4;  // k-group 0..3
    const int row0 = blockIdx.x * 64;

    const float4* A4 = reinterpret_cast<const float4*>(A);  // 32 float4 per row
    const uint4* B4 = reinterpret_cast<const uint4*>(WTb);  // 16 uint4 per col

    f32x4 acc[4][NT];
#pragma unroll
    for (int m = 0; m < 4; m++)
#pragma unroll
        for (int nt = 0; nt < NT; nt++) acc[m][nt] = (f32x4){0.f, 0.f, 0.f, 0.f};

    int rowm[4];
#pragma unroll
    for (int m = 0; m < 4; m++) {
        int r = row0 + m * 16 + r16;
        rowm[m] = r < M ? r : M - 1;  // clamp: stay in-bounds, stores are guarded
    }

    union U { uint4 u; bf16x8 v; };

#pragma unroll
    for (int kt = 0; kt < 4; kt++) {  // K=128 in 4 steps of 32
        U b[NT];
#pragma unroll
        for (int nt = 0; nt < NT; nt++)
            b[nt].u = B4[(size_t)(nt * 64 + wave * 16 + r16) * 16 + kt * 4 + g];
        U a[4];
#pragma unroll
        for (int m = 0; m < 4; m++) {
            float4 f0 = A4[(size_t)rowm[m] * 32 + kt * 8 + g * 2];
            float4 f1 = A4[(size_t)rowm[m] * 32 + kt * 8 + g * 2 + 1];
            a[m].u.x = f32_to_bf16_rne(f0.x) | (f32_to_bf16_rne(f0.y) << 16);
            a[m].u.y = f32_to_bf16_rne(f0.z) | (f32_to_bf16_rne(f0.w) << 16);
            a[m].u.z = f32_to_bf16_rne(f1.x) | (f32_to_bf16_rne(f1.y) << 16);
            a[m].u.w = f32_to_bf16_rne(f1.z) | (f32_to_bf16_rne(f1.w) << 16);
        }
#pragma unroll
        for (int m = 0; m < 4; m++)
#pragma unroll
            for (int nt = 0; nt < NT; nt++)
                acc[m][nt] = __builtin_amdgcn_mfma_f32_16x16x32_bf16(a[m].v, b[nt].v, acc[m][nt], 0, 0, 0);
    }

    // epilogue: row=(lane>>4)*4+reg, col=lane&15; pack col pairs via shfl_xor(1)
#pragma unroll
    for (int m = 0; m < 4; m++)
#pragma unroll
        for (int nt = 0; nt < NT; nt++)
#pragma unroll
            for (int r = 0; r < 4; r++) {
                int row = row0 + m * 16 + g * 4 + r;
                float v = acc[m][nt][r];
                float nb = __shfl_xor(v, 1);
                if ((r16 & 1) == 0 && row < M) {
                    uint32 p = f32_to_bf16_rne(v) | (f32_to_bf16_rne(nb) << 16);
                    int col = nt * 64 + wave * 16 + r16;
                    Cb[(size_t)row * (N / 2) + (col >> 1)] = p;
                }
            }
}

// ---------------- aggregate F=128: one wave/node, 8-deep unrolled gather --------
__global__ __launch_bounds__(256) void aggregate128_kernel(const uint32* __restrict__ hwb,
                                                           const u16* __restrict__ adj,
                                                           const int* __restrict__ deg,
                                                           const float* __restrict__ bias,
                                                           float* __restrict__ out) {
    int wave = (blockIdx.x * blockDim.x + threadIdx.x) >> 6;
    int lane = threadIdx.x & 63;
    if (wave >= N_NODES) return;
    int d = deg[wave];
    d = __builtin_amdgcn_readfirstlane(d);
    if (d > CAP) d = CAP;
    int myslot = adj[wave * CAP + lane];

    float ax = 0.f, ay = 0.f;
    int e = 0;
    for (; e + 8 <= d; e += 8) {
        int s0 = __shfl(myslot, e + 0), s1 = __shfl(myslot, e + 1);
        int s2 = __shfl(myslot, e + 2), s3 = __shfl(myslot, e + 3);
        int s4 = __shfl(myslot, e + 4), s5 = __shfl(myslot, e + 5);
        int s6 = __shfl(myslot, e + 6), s7 = __shfl(myslot, e + 7);
        uint32 v0 = hwb[s0 * 64 + lane], v1 = hwb[s1 * 64 + lane];
        uint32 v2 = hwb[s2 * 64 + lane], v3 = hwb[s3 * 64 + lane];
        uint32 v4 = hwb[s4 * 64 + lane], v5 = hwb[s5 * 64 + lane];
        uint32 v6 = hwb[s6 * 64 + lane], v7 = hwb[s7 * 64 + lane];
        ax += (bf16lo_to_f32(v0) + bf16lo_to_f32(v1)) + (bf16lo_to_f32(v2) + bf16lo_to_f32(v3)) +
              (bf16lo_to_f32(v4) + bf16lo_to_f32(v5)) + (bf16lo_to_f32(v6) + bf16lo_to_f32(v7));
        ay += (bf16hi_to_f32(v0) + bf16hi_to_f32(v1)) + (bf16hi_to_f32(v2) + bf16hi_to_f32(v3)) +
              (bf16hi_to_f32(v4) + bf16hi_to_f32(v5)) + (bf16hi_to_f32(v6) + bf16hi_to_f32(v7));
    }
    for (; e < d; e++) {
        int s = __shfl(myslot, e);
        uint32 v = hwb[s * 64 + lane];
        ax += bf16lo_to_f32(v);
        ay += bf16hi_to_f32(v);
    }
    float2 b = *reinterpret_cast<const float2*>(&bias[lane * 2]);
    ax += b.x;
    ay += b.y;
    *reinterpret_cast<float2*>(&out[(size_t)wave * 128 + lane * 2]) = make_float2(ax, ay);
}

// ---------------- aggregate F=64: two nodes/wave, 4-deep predicated unroll ------
__global__ __launch_bounds__(256) void aggregate64_kernel(const uint32* __restrict__ hwb,
                                                          const u16* __restrict__ adj,
                                                          const int* __restrict__ deg,
                                                          const float* __restrict__ bias,
                                                          float* __restrict__ out) {
    int wave = (blockIdx.x * blockDim.x + threadIdx.x) >> 6;
    int lane = threadIdx.x & 63;
    if (wave >= N_NODES / 2) return;
    const int half = lane >> 5;
    const int li = lane & 31;
    const int a = wave * 2;

    int slotA = adj[a * CAP + lane];
    int slotB = adj[(a + 1) * CAP + lane];
    int dmine = deg[a + half];
    int d0 = __shfl(dmine, 0);
    int d1 = __shfl(dmine, 32);
    if (d0 > CAP) d0 = CAP;
    if (d1 > CAP) d1 = CAP;
    int dH = half ? d1 : d0;
    int dmax = d0 > d1 ? d0 : d1;

    float ax = 0.f, ay = 0.f;
    int e = 0;
    for (; e + 4 <= dmax; e += 4) {
#pragma unroll
        for (int i = 0; i < 4; i++) {
            int sA = __shfl(slotA, e + i);
            int sB = __shfl(slotB, e + i);
            int s = half ? sB : sA;
            uint32 v = (e + i < dH) ? hwb[s * 32 + li] : 0u;
            ax += bf16lo_to_f32(v);
            ay += bf16hi_to_f32(v);
        }
    }
    for (; e < dmax; e++) {
        int sA = __shfl(slotA, e);
        int sB = __shfl(slotB, e);
        int s = half ? sB : sA;
        uint32 v = (e < dH) ? hwb[s * 32 + li] : 0u;
        ax += bf16lo_to_f32(v);
        ay += bf16hi_to_f32(v);
    }
    float2 b = *reinterpret_cast<const float2*>(&bias[li * 2]);
    ax += b.x;
    ay += b.y;
    *reinterpret_cast<float2*>(&out[(size_t)(a + half) * 64 + li * 2]) = make_float2(ax, ay);
}

extern "C" void kernel_launch(void* const* d_in, const int* in_sizes, int n_in,
                              void* d_out, int out_size, void* d_ws, size_t ws_size,
                              hipStream_t stream) {
    const float* x  = (const float*)d_in[0];
    const int*   ei = (const int*)d_in[1];
    const float* W1 = (const float*)d_in[2];
    const float* b1 = (const float*)d_in[3];
    const float* W2 = (const float*)d_in[4];
    const float* b2 = (const float*)d_in[5];
    const float* W3 = (const float*)d_in[6];
    const float* b3 = (const float*)d_in[7];

    float* o1 = (float*)d_out;
    float* o2 = o1 + (size_t)N_NODES * 128;
    float* o3 = o2 + (size_t)N_NODES * 128;

    char* ws = (char*)d_ws;
    uint32* hwb    = (uint32*)(ws);                 // h@W bf16-packed [M][64], 12.8 MB
    u16*    adj    = (u16*)(ws + 12800000);         // 6.4 MB
    int*    cursor = (int*)(ws + 19200000);         // 200 KB
    uint32* wt1    = (uint32*)(ws + 19400000);      // 32 KB
    uint32* wt2    = (uint32*)(ws + 19432768);      // 32 KB
    uint32* wt3    = (uint32*)(ws + 19465536);      // 16 KB

    zero_int_kernel<<<(N_NODES + 255) / 256, 256, 0, stream>>>(cursor, N_NODES);
    {
        int chunks = (N_EDGES + EPB - 1) / EPB;     // 391
        build_adj_kernel<<<chunks * 8, 256, 0, stream>>>(ei, cursor, adj);
    }
    wt_kernel<<<(128 * 64 + 255) / 256, 256, 0, stream>>>(W1, wt1, 128);
    wt_kernel<<<(128 * 64 + 255) / 256, 256, 0, stream>>>(W2, wt2, 128);
    wt_kernel<<<(64 * 64 + 255) / 256, 256, 0, stream>>>(W3, wt3, 64);

    const int gemm_grid = (N_NODES + 63) / 64;          // 782
    const int agg128_grid = (N_NODES * 64 + 255) / 256; // 12500
    const int agg64_grid = (N_NODES / 2 * 64 + 255) / 256;

    // layer 1
    mfma_gemm_kernel<128><<<gemm_grid, 256, 0, stream>>>(x, wt1, hwb, N_NODES);
    aggregate128_kernel<<<agg128_grid, 256, 0, stream>>>(hwb, adj, cursor, b1, o1);
    // layer 2
    mfma_gemm_kernel<128><<<gemm_grid, 256, 0, stream>>>(o1, wt2, hwb, N_NODES);
    aggregate128_kernel<<<agg128_grid, 256, 0, stream>>>(hwb, adj, cursor, b2, o2);
    // layer 3
    mfma_gemm_kernel<64><<<gemm_grid, 256, 0, stream>>>(o2, wt3, hwb, N_NODES);
    aggregate64_kernel<<<agg64_grid, 256, 0, stream>>>(hwb, adj, cursor, b3, o3);
}

// Round 5
// 192.524 us; speedup vs baseline: 1.8306x; 1.0569x over previous
//
#include <hip/hip_runtime.h>

#define N_NODES 50000
#define N_EDGES 800000
#define CAP 64

typedef unsigned int uint32;
typedef unsigned short u16;

typedef __attribute__((ext_vector_type(8))) short bf16x8;
typedef __attribute__((ext_vector_type(4))) float f32x4;

__device__ __forceinline__ uint32 f32_to_bf16_rne(float f) {
    uint32 u = __float_as_uint(f);
    u += 0x7fffu + ((u >> 16) & 1u);
    return u >> 16;
}
__device__ __forceinline__ float bf16lo_to_f32(uint32 v) { return __uint_as_float(v << 16); }
__device__ __forceinline__ float bf16hi_to_f32(uint32 v) { return __uint_as_float(v & 0xffff0000u); }

// ---------------- prep: zero cursor + W -> WT bf16 tables (one launch) ----------------
__global__ __launch_bounds__(256) void prep_kernel(const float* __restrict__ W1,
                                                   const float* __restrict__ W2,
                                                   const float* __restrict__ W3,
                                                   uint32* __restrict__ wt1,
                                                   uint32* __restrict__ wt2,
                                                   uint32* __restrict__ wt3,
                                                   int* __restrict__ cursor) {
    int b = blockIdx.x, tid = threadIdx.x;
    if (b < 196) {
        int i = b * 256 + tid;
        if (i < N_NODES) cursor[i] = 0;
        return;
    }
    b -= 196;
    const float* W;
    uint32* WT;
    int N;
    if (b < 32) { W = W1; WT = wt1; N = 128; }
    else if (b < 64) { W = W2; WT = wt2; N = 128; b -= 32; }
    else { W = W3; WT = wt3; N = 64; b -= 64; }
    int i = b * 256 + tid;
    if (i >= N * 64) return;
    int n = i >> 6, p = i & 63;
    WT[n * 64 + p] = f32_to_bf16_rne(W[(2 * p) * N + n]) |
                     (f32_to_bf16_rne(W[(2 * p + 1) * N + n]) << 16);
}

// ---------------- gather helper: sum rows hwb[s][*] over adjacency ----------------
__device__ __forceinline__ void gather_row(const uint32* __restrict__ hwb,
                                           int myslot, int d, int lane,
                                           float& ax, float& ay) {
    int e = 0;
    for (; e + 8 <= d; e += 8) {
        int s0 = __shfl(myslot, e + 0), s1 = __shfl(myslot, e + 1);
        int s2 = __shfl(myslot, e + 2), s3 = __shfl(myslot, e + 3);
        int s4 = __shfl(myslot, e + 4), s5 = __shfl(myslot, e + 5);
        int s6 = __shfl(myslot, e + 6), s7 = __shfl(myslot, e + 7);
        uint32 v0 = hwb[s0 * 64 + lane], v1 = hwb[s1 * 64 + lane];
        uint32 v2 = hwb[s2 * 64 + lane], v3 = hwb[s3 * 64 + lane];
        uint32 v4 = hwb[s4 * 64 + lane], v5 = hwb[s5 * 64 + lane];
        uint32 v6 = hwb[s6 * 64 + lane], v7 = hwb[s7 * 64 + lane];
        ax += (bf16lo_to_f32(v0) + bf16lo_to_f32(v1)) + (bf16lo_to_f32(v2) + bf16lo_to_f32(v3)) +
              (bf16lo_to_f32(v4) + bf16lo_to_f32(v5)) + (bf16lo_to_f32(v6) + bf16lo_to_f32(v7));
        ay += (bf16hi_to_f32(v0) + bf16hi_to_f32(v1)) + (bf16hi_to_f32(v2) + bf16hi_to_f32(v3)) +
              (bf16hi_to_f32(v4) + bf16hi_to_f32(v5)) + (bf16hi_to_f32(v6) + bf16hi_to_f32(v7));
    }
    for (; e < d; e++) {
        int s = __shfl(myslot, e);
        uint32 v = hwb[s * 64 + lane];
        ax += bf16lo_to_f32(v);
        ay += bf16hi_to_f32(v);
    }
}

// ---------------- MFMA epilogue: pack bf16 pairs, store ----------------
template <int N>
__device__ __forceinline__ void store_cb(f32x4 (&acc)[4][N / 64], uint32* __restrict__ Cb,
                                         int row0, int M, int wave, int lane) {
    constexpr int NT = N / 64;
    const int r16 = lane & 15;
    const int g = lane >> 4;
#pragma unroll
    for (int m = 0; m < 4; m++)
#pragma unroll
        for (int nt = 0; nt < NT; nt++)
#pragma unroll
            for (int r = 0; r < 4; r++) {
                int row = row0 + m * 16 + g * 4 + r;
                float v = acc[m][nt][r];
                float nb = __shfl_xor(v, 1);
                if ((r16 & 1) == 0 && row < M) {
                    uint32 p = f32_to_bf16_rne(v) | (f32_to_bf16_rne(nb) << 16);
                    int col = nt * 64 + wave * 16 + r16;
                    Cb[(size_t)row * (N / 2) + (col >> 1)] = p;
                }
            }
}

// ---------------- gemm1 body: A f32 global, converted in-register ----------------
__device__ __forceinline__ void gemm1_body(const float* __restrict__ A,
                                           const uint32* __restrict__ WTb,
                                           uint32* __restrict__ Cb, int M, int bid) {
    constexpr int N = 128, NT = 2;
    const int tid = threadIdx.x;
    const int wave = tid >> 6;
    const int lane = tid & 63;
    const int r16 = lane & 15;
    const int g = lane >> 4;
    const int row0 = bid * 64;

    const float4* A4 = reinterpret_cast<const float4*>(A);
    const uint4* B4 = reinterpret_cast<const uint4*>(WTb);

    f32x4 acc[4][NT];
#pragma unroll
    for (int m = 0; m < 4; m++)
#pragma unroll
        for (int nt = 0; nt < NT; nt++) acc[m][nt] = (f32x4){0.f, 0.f, 0.f, 0.f};

    int rowm[4];
#pragma unroll
    for (int m = 0; m < 4; m++) {
        int r = row0 + m * 16 + r16;
        rowm[m] = r < M ? r : M - 1;
    }
    union U { uint4 u; bf16x8 v; };
#pragma unroll
    for (int kt = 0; kt < 4; kt++) {
        U b[NT];
#pragma unroll
        for (int nt = 0; nt < NT; nt++)
            b[nt].u = B4[(size_t)(nt * 64 + wave * 16 + r16) * 16 + kt * 4 + g];
        U a[4];
#pragma unroll
        for (int m = 0; m < 4; m++) {
            float4 f0 = A4[(size_t)rowm[m] * 32 + kt * 8 + g * 2];
            float4 f1 = A4[(size_t)rowm[m] * 32 + kt * 8 + g * 2 + 1];
            a[m].u.x = f32_to_bf16_rne(f0.x) | (f32_to_bf16_rne(f0.y) << 16);
            a[m].u.y = f32_to_bf16_rne(f0.z) | (f32_to_bf16_rne(f0.w) << 16);
            a[m].u.z = f32_to_bf16_rne(f1.x) | (f32_to_bf16_rne(f1.y) << 16);
            a[m].u.w = f32_to_bf16_rne(f1.z) | (f32_to_bf16_rne(f1.w) << 16);
        }
#pragma unroll
        for (int m = 0; m < 4; m++)
#pragma unroll
            for (int nt = 0; nt < NT; nt++)
                acc[m][nt] = __builtin_amdgcn_mfma_f32_16x16x32_bf16(a[m].v, b[nt].v, acc[m][nt], 0, 0, 0);
    }
    store_cb<128>(acc, Cb, row0, M, wave, lane);
}

// ---------------- fused build (line-partitioned) + gemm1 ----------------
#define EPT 8
#define EPB (256 * EPT)
#define GEMM1_BLOCKS 782   // ceil(50000/64)
#define BUILD_CHUNKS 391   // ceil(800000/2048)

__global__ __launch_bounds__(256) void build_gemm1_kernel(const float* __restrict__ x,
                                                          const uint32* __restrict__ wt1,
                                                          uint32* __restrict__ hwb,
                                                          const int* __restrict__ ei,
                                                          int* __restrict__ cursor,
                                                          u16* __restrict__ adj) {
    if (blockIdx.x < GEMM1_BLOCKS) {
        gemm1_body(x, wt1, hwb, N_NODES, blockIdx.x);
        return;
    }
    const int bb = blockIdx.x - GEMM1_BLOCKS;
    const int part = bb & 7;           // partition <-> XCD (bijective under %8 dispatch)
    const int chunk = bb >> 3;
    const int base = chunk * EPB + threadIdx.x * EPT;
#pragma unroll
    for (int i = 0; i < EPT; i += 4) {
        int e = base + i;
        if (e + 3 < N_EDGES) {
            int4 s4 = *reinterpret_cast<const int4*>(&ei[e]);
            int4 d4 = *reinterpret_cast<const int4*>(&ei[N_EDGES + e]);
            int ss[4] = {s4.x, s4.y, s4.z, s4.w};
            int dd[4] = {d4.x, d4.y, d4.z, d4.w};
#pragma unroll
            for (int j = 0; j < 4; j++) {
                int d = dd[j];
                // line-partition: whole 64B cursor line (16 nodes) -> one partition
                if (((d >> 4) & 7) == part && (unsigned)d < (unsigned)N_NODES) {
                    int s = ss[j];
                    if ((unsigned)s >= (unsigned)N_NODES) s = 0;
                    int pos = atomicAdd(&cursor[d], 1);
                    if (pos < CAP) adj[d * CAP + pos] = (u16)s;
                }
            }
        } else {
            for (int j = 0; j < 4; j++) {
                int ee = e + j;
                if (ee < N_EDGES) {
                    int d = ei[N_EDGES + ee];
                    if (((d >> 4) & 7) == part && (unsigned)d < (unsigned)N_NODES) {
                        int s = ei[ee];
                        if ((unsigned)s >= (unsigned)N_NODES) s = 0;
                        int pos = atomicAdd(&cursor[d], 1);
                        if (pos < CAP) adj[d * CAP + pos] = (u16)s;
                    }
                }
            }
        }
    }
}

// ---------------- fused aggregate(layer l) + gemm(layer l+1 messages) ----------------
// Block: 64 nodes. 4 waves x 16 nodes aggregate -> o_l (f32) + LDS bf16 rows;
// then 64xN MFMA from LDS -> hw_out (bf16-packed messages for layer l+1).
template <int N>
__global__ __launch_bounds__(256) void agg_gemm_kernel(const uint32* __restrict__ hw_in,
                                                       const u16* __restrict__ adj,
                                                       const int* __restrict__ deg,
                                                       const float* __restrict__ bias,
                                                       float* __restrict__ o_out,
                                                       const uint32* __restrict__ WTb,
                                                       uint32* __restrict__ hw_out) {
    constexpr int NT = N / 64;
    constexpr int LDR = 68;  // uints per row: 272B, 16B-aligned rows, conflict-light
    __shared__ uint32 Asm[64 * LDR];

    const int tid = threadIdx.x;
    const int wave = tid >> 6;
    const int lane = tid & 63;
    const int base = blockIdx.x * 64;

    // ---- aggregate 16 nodes per wave ----
    for (int i = 0; i < 16; i++) {
        int n = base + wave * 16 + i;
        float ax = 0.f, ay = 0.f;
        if (n < N_NODES) {
            int d = deg[n];
            d = __builtin_amdgcn_readfirstlane(d);
            if (d > CAP) d = CAP;
            int myslot = adj[n * CAP + lane];
            gather_row(hw_in, myslot, d, lane, ax, ay);
            float2 b = *reinterpret_cast<const float2*>(&bias[lane * 2]);
            ax += b.x;
            ay += b.y;
            *reinterpret_cast<float2*>(&o_out[(size_t)n * 128 + lane * 2]) = make_float2(ax, ay);
        }
        Asm[(wave * 16 + i) * LDR + lane] = f32_to_bf16_rne(ax) | (f32_to_bf16_rne(ay) << 16);
    }
    __syncthreads();

    // ---- GEMM from LDS: hw_out[64 rows][N] = A(lds) @ W_next ----
    const int r16 = lane & 15;
    const int g = lane >> 4;
    const uint4* B4 = reinterpret_cast<const uint4*>(WTb);

    f32x4 acc[4][NT];
#pragma unroll
    for (int m = 0; m < 4; m++)
#pragma unroll
        for (int nt = 0; nt < NT; nt++) acc[m][nt] = (f32x4){0.f, 0.f, 0.f, 0.f};

    union U { uint4 u; bf16x8 v; };
#pragma unroll
    for (int kt = 0; kt < 4; kt++) {
        U b[NT];
#pragma unroll
        for (int nt = 0; nt < NT; nt++)
            b[nt].u = B4[(size_t)(nt * 64 + wave * 16 + r16) * 16 + kt * 4 + g];
        U a[4];
#pragma unroll
        for (int m = 0; m < 4; m++)
            a[m].u = *reinterpret_cast<const uint4*>(&Asm[(m * 16 + r16) * LDR + (kt * 4 + g) * 4]);
#pragma unroll
        for (int m = 0; m < 4; m++)
#pragma unroll
            for (int nt = 0; nt < NT; nt++)
                acc[m][nt] = __builtin_amdgcn_mfma_f32_16x16x32_bf16(a[m].v, b[nt].v, acc[m][nt], 0, 0, 0);
    }
    store_cb<N>(acc, hw_out, base, N_NODES, wave, lane);
}

// ---------------- aggregate F=64: two nodes/wave (final layer) ----------------
__global__ __launch_bounds__(256) void aggregate64_kernel(const uint32* __restrict__ hwb,
                                                          const u16* __restrict__ adj,
                                                          const int* __restrict__ deg,
                                                          const float* __restrict__ bias,
                                                          float* __restrict__ out) {
    int wave = (blockIdx.x * blockDim.x + threadIdx.x) >> 6;
    int lane = threadIdx.x & 63;
    if (wave >= N_NODES / 2) return;
    const int half = lane >> 5;
    const int li = lane & 31;
    const int a = wave * 2;

    int slotA = adj[a * CAP + lane];
    int slotB = adj[(a + 1) * CAP + lane];
    int dmine = deg[a + half];
    int d0 = __shfl(dmine, 0);
    int d1 = __shfl(dmine, 32);
    if (d0 > CAP) d0 = CAP;
    if (d1 > CAP) d1 = CAP;
    int dH = half ? d1 : d0;
    int dmax = d0 > d1 ? d0 : d1;

    float ax = 0.f, ay = 0.f;
    int e = 0;
    for (; e + 4 <= dmax; e += 4) {
#pragma unroll
        for (int i = 0; i < 4; i++) {
            int sA = __shfl(slotA, e + i);
            int sB = __shfl(slotB, e + i);
            int s = half ? sB : sA;
            uint32 v = (e + i < dH) ? hwb[s * 32 + li] : 0u;
            ax += bf16lo_to_f32(v);
            ay += bf16hi_to_f32(v);
        }
    }
    for (; e < dmax; e++) {
        int sA = __shfl(slotA, e);
        int sB = __shfl(slotB, e);
        int s = half ? sB : sA;
        uint32 v = (e < dH) ? hwb[s * 32 + li] : 0u;
        ax += bf16lo_to_f32(v);
        ay += bf16hi_to_f32(v);
    }
    float2 b = *reinterpret_cast<const float2*>(&bias[li * 2]);
    ax += b.x;
    ay += b.y;
    *reinterpret_cast<float2*>(&out[(size_t)(a + half) * 64 + li * 2]) = make_float2(ax, ay);
}

extern "C" void kernel_launch(void* const* d_in, const int* in_sizes, int n_in,
                              void* d_out, int out_size, void* d_ws, size_t ws_size,
                              hipStream_t stream) {
    const float* x  = (const float*)d_in[0];
    const int*   ei = (const int*)d_in[1];
    const float* W1 = (const float*)d_in[2];
    const float* b1 = (const float*)d_in[3];
    const float* W2 = (const float*)d_in[4];
    const float* b2 = (const float*)d_in[5];
    const float* W3 = (const float*)d_in[6];
    const float* b3 = (const float*)d_in[7];

    float* o1 = (float*)d_out;
    float* o2 = o1 + (size_t)N_NODES * 128;
    float* o3 = o2 + (size_t)N_NODES * 128;

    char* ws = (char*)d_ws;
    uint32* hwbA   = (uint32*)(ws);                 // 12.8 MB
    uint32* hwbB   = (uint32*)(ws + 12800000);      // 12.8 MB
    u16*    adj    = (u16*)(ws + 25600000);         // 6.4 MB
    int*    cursor = (int*)(ws + 32000000);         // 200 KB
    uint32* wt1    = (uint32*)(ws + 32200000);      // 32 KB
    uint32* wt2    = (uint32*)(ws + 32232768);      // 32 KB
    uint32* wt3    = (uint32*)(ws + 32265536);      // 16 KB

    // 1. prep: zero cursor + WT tables
    prep_kernel<<<276, 256, 0, stream>>>(W1, W2, W3, wt1, wt2, wt3, cursor);
    // 2. fused adjacency build + gemm1 (concurrent: 782 gemm blocks < resident capacity)
    build_gemm1_kernel<<<GEMM1_BLOCKS + BUILD_CHUNKS * 8, 256, 0, stream>>>(x, wt1, hwbA, ei, cursor, adj);
    // 3. agg1 (+b1 -> o1) fused with gemm2 -> hwbB
    agg_gemm_kernel<128><<<GEMM1_BLOCKS, 256, 0, stream>>>(hwbA, adj, cursor, b1, o1, wt2, hwbB);
    // 4. agg2 (+b2 -> o2) fused with gemm3 -> hwbA
    agg_gemm_kernel<64><<<GEMM1_BLOCKS, 256, 0, stream>>>(hwbB, adj, cursor, b2, o2, wt3, hwbA);
    // 5. agg3 (+b3 -> o3)
    aggregate64_kernel<<<(N_NODES / 2 * 64 + 255) / 256, 256, 0, stream>>>(hwbA, adj, cursor, b3, o3);
}

// Round 6
// 175.466 us; speedup vs baseline: 2.0085x; 1.0972x over previous
//
#include <hip/hip_runtime.h>

#define N_NODES 50000
#define N_EDGES 800000
#define CAP 64

typedef unsigned int uint32;
typedef unsigned short u16;

typedef __attribute__((ext_vector_type(8))) short bf16x8;
typedef __attribute__((ext_vector_type(4))) float f32x4;

__device__ __forceinline__ uint32 f32_to_bf16_rne(float f) {
    uint32 u = __float_as_uint(f);
    u += 0x7fffu + ((u >> 16) & 1u);
    return u >> 16;
}
__device__ __forceinline__ float bf16lo_to_f32(uint32 v) { return __uint_as_float(v << 16); }
__device__ __forceinline__ float bf16hi_to_f32(uint32 v) { return __uint_as_float(v & 0xffff0000u); }

// ---------------- prep: zero cursor + W -> WT bf16 tables (one launch) ----------------
__global__ __launch_bounds__(256) void prep_kernel(const float* __restrict__ W1,
                                                   const float* __restrict__ W2,
                                                   const float* __restrict__ W3,
                                                   uint32* __restrict__ wt1,
                                                   uint32* __restrict__ wt2,
                                                   uint32* __restrict__ wt3,
                                                   int* __restrict__ cursor) {
    int b = blockIdx.x, tid = threadIdx.x;
    if (b < 196) {
        int i = b * 256 + tid;
        if (i < N_NODES) cursor[i] = 0;
        return;
    }
    b -= 196;
    const float* W;
    uint32* WT;
    int N;
    if (b < 32) { W = W1; WT = wt1; N = 128; }
    else if (b < 64) { W = W2; WT = wt2; N = 128; b -= 32; }
    else { W = W3; WT = wt3; N = 64; b -= 64; }
    int i = b * 256 + tid;
    if (i >= N * 64) return;
    int n = i >> 6, p = i & 63;
    WT[n * 64 + p] = f32_to_bf16_rne(W[(2 * p) * N + n]) |
                     (f32_to_bf16_rne(W[(2 * p + 1) * N + n]) << 16);
}

// ---- paired-edge gather over 64-uint (128-feat) rows: lane halves take e / e+1 ----
// On return all lanes hold full sums; lane li<32 covers feats 4li..4li+3.
__device__ __forceinline__ void gather_pair(const uint32* __restrict__ hwb,
                                            int myslot, int d, int lane,
                                            float& ax, float& ay, float& az, float& aw) {
    const int h = lane >> 5;
    const int li = lane & 31;
    int e = 0;
    for (; e + 16 <= d; e += 16) {
        uint2 v[8];
#pragma unroll
        for (int j = 0; j < 8; j++) {
            int s = __shfl(myslot, e + 2 * j + h);
            v[j] = *reinterpret_cast<const uint2*>(&hwb[(size_t)s * 64 + li * 2]);
        }
#pragma unroll
        for (int j = 0; j < 8; j++) {
            ax += bf16lo_to_f32(v[j].x); ay += bf16hi_to_f32(v[j].x);
            az += bf16lo_to_f32(v[j].y); aw += bf16hi_to_f32(v[j].y);
        }
    }
    for (; e < d; e += 2) {
        int idx = e + h;
        int s = __shfl(myslot, idx < d ? idx : e);
        uint2 v = make_uint2(0u, 0u);
        if (idx < d) v = *reinterpret_cast<const uint2*>(&hwb[(size_t)s * 64 + li * 2]);
        ax += bf16lo_to_f32(v.x); ay += bf16hi_to_f32(v.x);
        az += bf16lo_to_f32(v.y); aw += bf16hi_to_f32(v.y);
    }
    ax += __shfl_xor(ax, 32);
    ay += __shfl_xor(ay, 32);
    az += __shfl_xor(az, 32);
    aw += __shfl_xor(aw, 32);
}

// ---------------- MFMA epilogue helpers ----------------
__device__ __forceinline__ void pack_store(uint32* __restrict__ Cb, int rowstride_u,
                                           int row, int col, int r16, float v) {
    float nb = __shfl_xor(v, 1);
    if ((r16 & 1) == 0) {
        uint32 p = f32_to_bf16_rne(v) | (f32_to_bf16_rne(nb) << 16);
        Cb[(size_t)row * rowstride_u + (col >> 1)] = p;
    }
}

// ---------------- gemm1 body: A f32 global, converted in-register (64-row blocks) ----
__device__ __forceinline__ void gemm1_body(const float* __restrict__ A,
                                           const uint32* __restrict__ WTb,
                                           uint32* __restrict__ Cb, int M, int bid) {
    constexpr int NT = 2;
    const int tid = threadIdx.x;
    const int wave = tid >> 6;
    const int lane = tid & 63;
    const int r16 = lane & 15;
    const int g = lane >> 4;
    const int row0 = bid * 64;

    const float4* A4 = reinterpret_cast<const float4*>(A);
    const uint4* B4 = reinterpret_cast<const uint4*>(WTb);

    f32x4 acc[4][NT];
#pragma unroll
    for (int m = 0; m < 4; m++)
#pragma unroll
        for (int nt = 0; nt < NT; nt++) acc[m][nt] = (f32x4){0.f, 0.f, 0.f, 0.f};

    int rowm[4];
#pragma unroll
    for (int m = 0; m < 4; m++) {
        int r = row0 + m * 16 + r16;
        rowm[m] = r < M ? r : M - 1;
    }
    union U { uint4 u; bf16x8 v; };
#pragma unroll
    for (int kt = 0; kt < 4; kt++) {
        U b[NT];
#pragma unroll
        for (int nt = 0; nt < NT; nt++)
            b[nt].u = B4[(size_t)(nt * 64 + wave * 16 + r16) * 16 + kt * 4 + g];
        U a[4];
#pragma unroll
        for (int m = 0; m < 4; m++) {
            float4 f0 = A4[(size_t)rowm[m] * 32 + kt * 8 + g * 2];
            float4 f1 = A4[(size_t)rowm[m] * 32 + kt * 8 + g * 2 + 1];
            a[m].u.x = f32_to_bf16_rne(f0.x) | (f32_to_bf16_rne(f0.y) << 16);
            a[m].u.y = f32_to_bf16_rne(f0.z) | (f32_to_bf16_rne(f0.w) << 16);
            a[m].u.z = f32_to_bf16_rne(f1.x) | (f32_to_bf16_rne(f1.y) << 16);
            a[m].u.w = f32_to_bf16_rne(f1.z) | (f32_to_bf16_rne(f1.w) << 16);
        }
#pragma unroll
        for (int m = 0; m < 4; m++)
#pragma unroll
            for (int nt = 0; nt < NT; nt++)
                acc[m][nt] = __builtin_amdgcn_mfma_f32_16x16x32_bf16(a[m].v, b[nt].v, acc[m][nt], 0, 0, 0);
    }
#pragma unroll
    for (int m = 0; m < 4; m++)
#pragma unroll
        for (int nt = 0; nt < NT; nt++)
#pragma unroll
            for (int r = 0; r < 4; r++) {
                int row = row0 + m * 16 + g * 4 + r;
                if (row < M)
                    pack_store(Cb, 64, row, nt * 64 + wave * 16 + r16, r16, acc[m][nt][r]);
            }
}

// ---------------- fused build (line-partitioned) + gemm1 ----------------
#define EPT 8
#define EPB (256 * EPT)
#define GEMM1_BLOCKS 782   // ceil(50000/64)
#define BUILD_CHUNKS 391   // ceil(800000/2048)

__global__ __launch_bounds__(256) void build_gemm1_kernel(const float* __restrict__ x,
                                                          const uint32* __restrict__ wt1,
                                                          uint32* __restrict__ hwb,
                                                          const int* __restrict__ ei,
                                                          int* __restrict__ cursor,
                                                          u16* __restrict__ adj) {
    if (blockIdx.x < GEMM1_BLOCKS) {
        gemm1_body(x, wt1, hwb, N_NODES, blockIdx.x);
        return;
    }
    const int bb = blockIdx.x - GEMM1_BLOCKS;
    const int part = bb & 7;
    const int chunk = bb >> 3;
    const int base = chunk * EPB + threadIdx.x * EPT;
#pragma unroll
    for (int i = 0; i < EPT; i += 4) {
        int e = base + i;
        if (e + 3 < N_EDGES) {
            int4 s4 = *reinterpret_cast<const int4*>(&ei[e]);
            int4 d4 = *reinterpret_cast<const int4*>(&ei[N_EDGES + e]);
            int ss[4] = {s4.x, s4.y, s4.z, s4.w};
            int dd[4] = {d4.x, d4.y, d4.z, d4.w};
#pragma unroll
            for (int j = 0; j < 4; j++) {
                int d = dd[j];
                if (((d >> 4) & 7) == part && (unsigned)d < (unsigned)N_NODES) {
                    int s = ss[j];
                    if ((unsigned)s >= (unsigned)N_NODES) s = 0;
                    int pos = atomicAdd(&cursor[d], 1);
                    if (pos < CAP) adj[d * CAP + pos] = (u16)s;
                }
            }
        } else {
            for (int j = 0; j < 4; j++) {
                int ee = e + j;
                if (ee < N_EDGES) {
                    int d = ei[N_EDGES + ee];
                    if (((d >> 4) & 7) == part && (unsigned)d < (unsigned)N_NODES) {
                        int s = ei[ee];
                        if ((unsigned)s >= (unsigned)N_NODES) s = 0;
                        int pos = atomicAdd(&cursor[d], 1);
                        if (pos < CAP) adj[d * CAP + pos] = (u16)s;
                    }
                }
            }
        }
    }
}

// ---------------- fused aggregate(layer l) + gemm(layer l+1 messages) ----------------
// Block: 16 nodes (grid 3125 exact). 4 waves x 4 nodes, paired-edge gather;
// then 16xN MFMA from LDS -> hw_out. High grid count => latency hiding for gather.
template <int N>
__global__ __launch_bounds__(256) void agg_gemm_kernel(const uint32* __restrict__ hw_in,
                                                       const u16* __restrict__ adj,
                                                       const int* __restrict__ deg,
                                                       const float* __restrict__ bias,
                                                       float* __restrict__ o_out,
                                                       const uint32* __restrict__ WTb,
                                                       uint32* __restrict__ hw_out) {
    constexpr int TPW = N / 64;  // 16-col tiles per wave: 2 (N=128) or 1 (N=64)
    constexpr int LDR = 68;
    __shared__ uint32 Asm[16 * LDR];

    const int tid = threadIdx.x;
    const int wave = tid >> 6;
    const int lane = tid & 63;
    const int li = lane & 31;
    const int base = blockIdx.x * 16;
    const float4* bias4 = reinterpret_cast<const float4*>(bias);

#pragma unroll
    for (int i = 0; i < 4; i++) {
        int n = base + wave * 4 + i;
        int d = __builtin_amdgcn_readfirstlane(deg[n]);
        if (d > CAP) d = CAP;
        int myslot = adj[n * CAP + lane];
        float ax = 0.f, ay = 0.f, az = 0.f, aw = 0.f;
        gather_pair(hw_in, myslot, d, lane, ax, ay, az, aw);
        if (lane < 32) {
            float4 b = bias4[li];
            ax += b.x; ay += b.y; az += b.z; aw += b.w;
            *reinterpret_cast<float4*>(&o_out[(size_t)n * 128 + li * 4]) =
                make_float4(ax, ay, az, aw);
            uint2 p;
            p.x = f32_to_bf16_rne(ax) | (f32_to_bf16_rne(ay) << 16);
            p.y = f32_to_bf16_rne(az) | (f32_to_bf16_rne(aw) << 16);
            *reinterpret_cast<uint2*>(&Asm[(wave * 4 + i) * LDR + li * 2]) = p;
        }
    }
    __syncthreads();

    // ---- GEMM 16 x N from LDS ----
    const int r16 = lane & 15;
    const int g = lane >> 4;
    const uint4* B4 = reinterpret_cast<const uint4*>(WTb);

    f32x4 acc[TPW];
#pragma unroll
    for (int nt = 0; nt < TPW; nt++) acc[nt] = (f32x4){0.f, 0.f, 0.f, 0.f};

    union U { uint4 u; bf16x8 v; };
#pragma unroll
    for (int kt = 0; kt < 4; kt++) {
        U a;
        a.u = *reinterpret_cast<const uint4*>(&Asm[r16 * LDR + (kt * 4 + g) * 4]);
        U b[TPW];
#pragma unroll
        for (int nt = 0; nt < TPW; nt++) {
            int col = (wave * TPW + nt) * 16 + r16;
            b[nt].u = B4[(size_t)col * 16 + kt * 4 + g];
        }
#pragma unroll
        for (int nt = 0; nt < TPW; nt++)
            acc[nt] = __builtin_amdgcn_mfma_f32_16x16x32_bf16(a.v, b[nt].v, acc[nt], 0, 0, 0);
    }
#pragma unroll
    for (int nt = 0; nt < TPW; nt++)
#pragma unroll
        for (int r = 0; r < 4; r++) {
            int row = base + g * 4 + r;
            pack_store(hw_out, N / 2, row, (wave * TPW + nt) * 16 + r16, r16, acc[nt][r]);
        }
}

// ---------------- final aggregate F=64: 1 node/wave, quad-edge uint2 gather --------
__global__ __launch_bounds__(256) void aggregate64_kernel(const uint32* __restrict__ hwb,
                                                          const u16* __restrict__ adj,
                                                          const int* __restrict__ deg,
                                                          const float* __restrict__ bias,
                                                          float* __restrict__ out) {
    int n = (blockIdx.x * blockDim.x + threadIdx.x) >> 6;
    if (n >= N_NODES) return;
    const int lane = threadIdx.x & 63;
    const int q = lane >> 4;
    const int li = lane & 15;
    int d = __builtin_amdgcn_readfirstlane(deg[n]);
    if (d > CAP) d = CAP;
    int myslot = adj[n * CAP + lane];

    float ax = 0.f, ay = 0.f, az = 0.f, aw = 0.f;
    int e = 0;
    for (; e + 32 <= d; e += 32) {
        uint2 v[8];
#pragma unroll
        for (int j = 0; j < 8; j++) {
            int s = __shfl(myslot, e + 4 * j + q);
            v[j] = *reinterpret_cast<const uint2*>(&hwb[(size_t)s * 32 + li * 2]);
        }
#pragma unroll
        for (int j = 0; j < 8; j++) {
            ax += bf16lo_to_f32(v[j].x); ay += bf16hi_to_f32(v[j].x);
            az += bf16lo_to_f32(v[j].y); aw += bf16hi_to_f32(v[j].y);
        }
    }
    for (; e < d; e += 4) {
        int idx = e + q;
        int s = __shfl(myslot, idx < d ? idx : e);
        uint2 v = make_uint2(0u, 0u);
        if (idx < d) v = *reinterpret_cast<const uint2*>(&hwb[(size_t)s * 32 + li * 2]);
        ax += bf16lo_to_f32(v.x); ay += bf16hi_to_f32(v.x);
        az += bf16lo_to_f32(v.y); aw += bf16hi_to_f32(v.y);
    }
    ax += __shfl_xor(ax, 32); ay += __shfl_xor(ay, 32);
    az += __shfl_xor(az, 32); aw += __shfl_xor(aw, 32);
    ax += __shfl_xor(ax, 16); ay += __shfl_xor(ay, 16);
    az += __shfl_xor(az, 16); aw += __shfl_xor(aw, 16);
    if (lane < 16) {
        const float4* bias4 = reinterpret_cast<const float4*>(bias);
        float4 b = bias4[li];
        *reinterpret_cast<float4*>(&out[(size_t)n * 64 + li * 4]) =
            make_float4(ax + b.x, ay + b.y, az + b.z, aw + b.w);
    }
}

extern "C" void kernel_launch(void* const* d_in, const int* in_sizes, int n_in,
                              void* d_out, int out_size, void* d_ws, size_t ws_size,
                              hipStream_t stream) {
    const float* x  = (const float*)d_in[0];
    const int*   ei = (const int*)d_in[1];
    const float* W1 = (const float*)d_in[2];
    const float* b1 = (const float*)d_in[3];
    const float* W2 = (const float*)d_in[4];
    const float* b2 = (const float*)d_in[5];
    const float* W3 = (const float*)d_in[6];
    const float* b3 = (const float*)d_in[7];

    float* o1 = (float*)d_out;
    float* o2 = o1 + (size_t)N_NODES * 128;
    float* o3 = o2 + (size_t)N_NODES * 128;

    char* ws = (char*)d_ws;
    uint32* hwbA   = (uint32*)(ws);                 // 12.8 MB
    uint32* hwbB   = (uint32*)(ws + 12800000);      // 12.8 MB
    u16*    adj    = (u16*)(ws + 25600000);         // 6.4 MB
    int*    cursor = (int*)(ws + 32000000);         // 200 KB
    uint32* wt1    = (uint32*)(ws + 32200000);      // 32 KB
    uint32* wt2    = (uint32*)(ws + 32232768);      // 32 KB
    uint32* wt3    = (uint32*)(ws + 32265536);      // 16 KB

    // 1. prep: zero cursor + WT tables
    prep_kernel<<<276, 256, 0, stream>>>(W1, W2, W3, wt1, wt2, wt3, cursor);
    // 2. fused adjacency build + gemm1
    build_gemm1_kernel<<<GEMM1_BLOCKS + BUILD_CHUNKS * 8, 256, 0, stream>>>(x, wt1, hwbA, ei, cursor, adj);
    // 3. agg1 (+b1 -> o1) fused with gemm2 -> hwbB   (3125 blocks, 16 nodes each)
    agg_gemm_kernel<128><<<3125, 256, 0, stream>>>(hwbA, adj, cursor, b1, o1, wt2, hwbB);
    // 4. agg2 (+b2 -> o2) fused with gemm3 -> hwbA
    agg_gemm_kernel<64><<<3125, 256, 0, stream>>>(hwbB, adj, cursor, b2, o2, wt3, hwbA);
    // 5. agg3 (+b3 -> o3)
    aggregate64_kernel<<<12500, 256, 0, stream>>>(hwbA, adj, cursor, b3, o3);
}